// Round 1
// baseline (144.599 us; speedup 1.0000x reference)
//
#include <hip/hip_runtime.h>

#define NN 50000
#define KK 20

// Static device scratch instead of d_ws (tests the "workspace poison fill is
// conditional on ws usage" hypothesis; also guarantees layout control).
// pool layout: [half h][A/B][node*32 + ch] bf16 -> 64 B per (node, half, side)
__device__ __align__(256) ushort g_pool[2][2][NN * 32];   // 12.8 MB
__device__ __align__(256) float  g_sup[NN * KK];          // 4 MB

static __device__ __forceinline__ ushort f2bf(float f) {
    unsigned int u = __float_as_uint(f);
    unsigned int r = (u + 0x7FFFu + ((u >> 16) & 1u)) >> 16;   // RNE
    return (ushort)r;
}
static __device__ __forceinline__ float bfl(unsigned int u) {   // low bf16 -> f32
    return __uint_as_float(u << 16);
}
static __device__ __forceinline__ float bfh(unsigned int u) {   // high bf16 -> f32
    return __uint_as_float(u & 0xffff0000u);
}

// ---------------------------------------------------------------------------
// Kernel 1: GEMM prep (R7 register-tile structure, unchanged math) +
//   (a) NEW: sup[n][k] precompute (tanh via exp, once -- edge no longer
//       recomputes it per channel-phase)
//   (b) NEW: stores go to half-split pool planes for L2-resident gathers.
// ---------------------------------------------------------------------------
__global__ __launch_bounds__(256) void prep_kernel(
    const float* __restrict__ x,    // [64][NN]
    const float* __restrict__ W,    // [64][128]
    const float* __restrict__ b,    // [64]
    const float* __restrict__ dis,  // [NN][KK]
    const float* __restrict__ att_w,// [KK]
    const float* __restrict__ att_b)// [1]
{
    __shared__ float At[64][66];    // W1-W2, transposed
    __shared__ float Bt[64][66];    // W2, transposed
    __shared__ float xt[64][132];   // x tile, 128 nodes
    __shared__ float disL[128 * KK];
    __shared__ float scalerL[128];

    const int t  = threadIdx.x;
    const int n0 = blockIdx.x * 128;     // grid 391; tail block has 80 valid

    for (int i = t; i < 64 * 64; i += 256) {
        int c = i >> 6, ci = i & 63;
        float w1 = W[c * 128 + ci];
        float w2 = W[c * 128 + 64 + ci];
        At[ci][c] = w1 - w2;
        Bt[ci][c] = w2;
    }
    {
        const int q  = t & 31;           // float4 index within the 128 nodes
        const int cb = t >> 5;           // 0..7
        const float4* x4 = (const float4*)x;   // [64][12500] float4
        const int nq = (n0 >> 2) + q;
        #pragma unroll
        for (int i = 0; i < 8; i++) {
            const int ci = cb * 8 + i;
            float4 v = (nq < 12500) ? x4[ci * 12500 + nq]
                                    : float4{0.f, 0.f, 0.f, 0.f};
            *(float4*)&xt[ci][q * 4] = v;
        }
    }
    for (int i = t; i < 128 * KK; i += 256) {
        const int gi = n0 * KK + i;
        disL[i] = (gi < NN * KK) ? dis[gi] : 0.f;
    }
    __syncthreads();

    // scaler[n] = tanh(att_w . dis[n] + att_b) + 1 = 2*sigmoid(2z)
    if (t < 128) {
        float z = att_b[0];
        #pragma unroll
        for (int k = 0; k < KK; k++) z += att_w[k] * disL[t * KK + k];
        scalerL[t] = 2.f / (1.f + __expf(-2.f * z));
    }
    __syncthreads();

    // sup[n][k] = 2*sigmoid(-dis*scaler)
    for (int i = t; i < 128 * KK; i += 256) {
        const int gi = n0 * KK + i;
        if (gi < NN * KK)
            g_sup[gi] = 2.f / (1.f + __expf(disL[i] * scalerL[i / KK]));
    }

    // ---- GEMM: 2 adjacent channels x 16 nodes per thread ----
    const int c2 = t & 31;     // channel pair: channels 2*c2, 2*c2+1
    const int g  = t >> 5;     // node group 0..7 -> nodes g*16 .. g*16+15

    float aA0[16], aA1[16], aB0[16], aB1[16];
    #pragma unroll
    for (int j = 0; j < 16; j++) { aA0[j]=0.f; aA1[j]=0.f; aB0[j]=0.f; aB1[j]=0.f; }

    for (int ci = 0; ci < 64; ci++) {
        const float2 a  = *(const float2*)&At[ci][c2 * 2];
        const float2 w2 = *(const float2*)&Bt[ci][c2 * 2];
        const float4* xr = (const float4*)&xt[ci][g * 16];
        #pragma unroll
        for (int q = 0; q < 4; q++) {
            float4 xv = xr[q];
            aA0[q*4+0] += a.x*xv.x;  aA1[q*4+0] += a.y*xv.x;
            aB0[q*4+0] += w2.x*xv.x; aB1[q*4+0] += w2.y*xv.x;
            aA0[q*4+1] += a.x*xv.y;  aA1[q*4+1] += a.y*xv.y;
            aB0[q*4+1] += w2.x*xv.y; aB1[q*4+1] += w2.y*xv.y;
            aA0[q*4+2] += a.x*xv.z;  aA1[q*4+2] += a.y*xv.z;
            aB0[q*4+2] += w2.x*xv.z; aB1[q*4+2] += w2.y*xv.z;
            aA0[q*4+3] += a.x*xv.w;  aA1[q*4+3] += a.y*xv.w;
            aB0[q*4+3] += w2.x*xv.w; aB1[q*4+3] += w2.y*xv.w;
        }
    }

    // stores: pair c2 = channels (2c2, 2c2+1) -> half h = c2>>4, pair pp = c2&15
    const float b0 = b[c2 * 2], b1 = b[c2 * 2 + 1];
    const int h  = c2 >> 4;
    const int pp = c2 & 15;
    unsigned int* pool32 = (unsigned int*)g_pool;
    const size_t baseA = (size_t)(h * 2 + 0) * NN * 16;
    const size_t baseB = (size_t)(h * 2 + 1) * NN * 16;
    #pragma unroll
    for (int j = 0; j < 16; j++) {
        const int n = n0 + g * 16 + j;
        if (n < NN) {
            pool32[baseA + (size_t)n * 16 + pp] =
                (unsigned int)f2bf(aA0[j] + b0) | ((unsigned int)f2bf(aA1[j] + b1) << 16);
            pool32[baseB + (size_t)n * 16 + pp] =
                (unsigned int)f2bf(aB0[j]) | ((unsigned int)f2bf(aB1[j]) << 16);
        }
    }
}

// ---------------------------------------------------------------------------
// Kernel 2: gather + relu + suppression + max over K.
// Channel-HALF phases: phase h gathers only 32 channels (64 B/endpoint) from a
// 6.4 MB pool -> mostly per-XCD-L2-resident (vs 12.8 MB before). 1-D grid,
// h = bx/3125 so dispatch order time-separates the two pools. Streaming data
// (indices, sup, out) uses nontemporal hints to protect pool residency.
// Geometry: 8 edge slots x 8 channel-quads per wave, uint2/lane, 24-padded
// (pad slots read node 0 with sup=0 -> contributes exactly 0 to the max).
// ---------------------------------------------------------------------------
__global__ __launch_bounds__(256) void edge_kernel(
    const int* __restrict__ ej,      // edge_index[0] : [NN][KK]  (x_j -> B pool)
    const int* __restrict__ ei,      // edge_index[1] : [NN][KK]  (x_i -> A pool)
    float* __restrict__ out)         // [64][NN]
{
    __shared__ float tile[16][36];   // [node][half-channel], stride 36 (16B-aligned rows)

    const int t    = threadIdx.x;
    const int lane = t & 63;
    const int w    = t >> 6;            // wave 0..3
    const int g    = lane >> 3;         // edge slot 0..7
    const int q    = lane & 7;          // channel quad 0..7 (4 ch of the half)
    const int bx   = blockIdx.x;        // 0..6249
    const int h    = (bx >= 3125) ? 1 : 0;
    const int n0   = (bx - h * 3125) * 16;
    const int nb   = n0 + w * 4;

    const char* pA = (const char*)&g_pool[h][0][0];
    const char* pB = (const char*)&g_pool[h][1][0];

    int offI[4], offJ[4]; float sup4[4];
    #pragma unroll
    for (int s = 0; s < 4; s++) {
        const int n = nb + s;
        int ii = 0, jj = 0; float sp = 0.f;
        if (lane < KK) {
            ii = __builtin_nontemporal_load(&ei[n * KK + lane]);
            jj = __builtin_nontemporal_load(&ej[n * KK + lane]);
            sp = __builtin_nontemporal_load(&g_sup[n * KK + lane]);
        }
        offI[s] = ii << 6;      // byte offset: node * 64
        offJ[s] = jj << 6;
        sup4[s] = sp;           // 0 for lanes >= 20 -> pad slots contribute 0
    }

    #pragma unroll
    for (int s = 0; s < 4; s++) {
        float4 m = {0.f, 0.f, 0.f, 0.f};
        #pragma unroll
        for (int r = 0; r < 3; r++) {           // 3 rounds x 8 slots = 24 (>=20)
            const int   src = r * 8 + g;        // 0..23; 20..23 are zero-pads
            const int   oi  = __shfl(offI[s], src);
            const int   oj  = __shfl(offJ[s], src);
            const float sp  = __shfl(sup4[s], src);
            const uint2 a   = *(const uint2*)(pA + oi + q * 8);
            const uint2 bb  = *(const uint2*)(pB + oj + q * 8);
            float v;
            v = fmaxf(bfl(a.x) + bfl(bb.x), 0.f) * sp;  m.x = fmaxf(m.x, v);
            v = fmaxf(bfh(a.x) + bfh(bb.x), 0.f) * sp;  m.y = fmaxf(m.y, v);
            v = fmaxf(bfl(a.y) + bfl(bb.y), 0.f) * sp;  m.z = fmaxf(m.z, v);
            v = fmaxf(bfh(a.y) + bfh(bb.y), 0.f) * sp;  m.w = fmaxf(m.w, v);
        }
        #pragma unroll
        for (int mask = 8; mask <= 32; mask <<= 1) {    // reduce across 8 slots
            m.x = fmaxf(m.x, __shfl_xor(m.x, mask));
            m.y = fmaxf(m.y, __shfl_xor(m.y, mask));
            m.z = fmaxf(m.z, __shfl_xor(m.z, mask));
            m.w = fmaxf(m.w, __shfl_xor(m.w, mask));
        }
        if (g == 0) *(float4*)&tile[w * 4 + s][q * 4] = m;
    }
    __syncthreads();

    #pragma unroll
    for (int it = 0; it < 2; it++) {
        const int c  = it * 16 + (t >> 4);   // half-channel 0..31
        const int nl = t & 15;
        __builtin_nontemporal_store(tile[nl][c],
                                    &out[(size_t)(h * 32 + c) * NN + n0 + nl]);
    }
}

extern "C" void kernel_launch(void* const* d_in, const int* in_sizes, int n_in,
                              void* d_out, int out_size, void* d_ws, size_t ws_size,
                              hipStream_t stream) {
    const float* x     = (const float*)d_in[0];
    const int*   e     = (const int*)d_in[1];    // [2][NN][KK]
    const float* dis   = (const float*)d_in[2];
    const float* W     = (const float*)d_in[3];
    const float* b     = (const float*)d_in[4];
    const float* att_w = (const float*)d_in[5];
    const float* att_b = (const float*)d_in[6];
    float* out = (float*)d_out;

    (void)d_ws; (void)ws_size;   // intentionally unused: static __device__ scratch

    prep_kernel<<<(NN + 127) / 128, 256, 0, stream>>>(x, W, b, dis, att_w, att_b);
    edge_kernel<<<2 * 3125, 256, 0, stream>>>(e, e + NN * KK, out);
}

// Round 2
// 133.479 us; speedup vs baseline: 1.0833x; 1.0833x over previous
//
#include <hip/hip_runtime.h>

#define NN 50000
#define KK 20

// Static device scratch (d_ws poison fill happens regardless; static keeps
// layout control and frees us from ws entirely).
__device__ __align__(256) ushort g_poolA[NN * 64];   // [NN][64] bf16, node-major
__device__ __align__(256) ushort g_poolB[NN * 64];
__device__ __align__(256) float  g_sup[NN * KK];     // precomputed suppression

static __device__ __forceinline__ ushort f2bf(float f) {
    unsigned int u = __float_as_uint(f);
    unsigned int r = (u + 0x7FFFu + ((u >> 16) & 1u)) >> 16;   // RNE
    return (ushort)r;
}
static __device__ __forceinline__ float bfl(unsigned int u) {   // low bf16 -> f32
    return __uint_as_float(u << 16);
}
static __device__ __forceinline__ float bfh(unsigned int u) {   // high bf16 -> f32
    return __uint_as_float(u & 0xffff0000u);
}

// ---------------------------------------------------------------------------
// Kernel 1: yA[n][c] = (W1-W2)@x + b ; yB[n][c] = W2@x, node-major bf16
// (R7 register-tile structure: 2 adjacent channels x 16 nodes per thread)
// + sup[n][k] = 2*sigmoid(-dis*scaler) precompute (hoisted out of edge).
// ---------------------------------------------------------------------------
__global__ __launch_bounds__(256) void prep_kernel(
    const float* __restrict__ x,    // [64][NN]
    const float* __restrict__ W,    // [64][128]
    const float* __restrict__ b,    // [64]
    const float* __restrict__ dis,  // [NN][KK]
    const float* __restrict__ att_w,// [KK]
    const float* __restrict__ att_b)// [1]
{
    __shared__ float At[64][66];    // W1-W2, transposed
    __shared__ float Bt[64][66];    // W2, transposed
    __shared__ float xt[64][132];   // x tile, 128 nodes
    __shared__ float disL[128 * KK];
    __shared__ float scalerL[128];

    const int t  = threadIdx.x;
    const int n0 = blockIdx.x * 128;     // grid 391; tail block has 80 valid

    for (int i = t; i < 64 * 64; i += 256) {
        int c = i >> 6, ci = i & 63;
        float w1 = W[c * 128 + ci];
        float w2 = W[c * 128 + 64 + ci];
        At[ci][c] = w1 - w2;
        Bt[ci][c] = w2;
    }
    {
        const int q  = t & 31;           // float4 index within the 128 nodes
        const int cb = t >> 5;           // 0..7
        const float4* x4 = (const float4*)x;   // [64][12500] float4
        const int nq = (n0 >> 2) + q;
        #pragma unroll
        for (int i = 0; i < 8; i++) {
            const int ci = cb * 8 + i;
            float4 v = (nq < 12500) ? x4[ci * 12500 + nq]
                                    : float4{0.f, 0.f, 0.f, 0.f};
            *(float4*)&xt[ci][q * 4] = v;
        }
    }
    for (int i = t; i < 128 * KK; i += 256) {
        const int gi = n0 * KK + i;
        disL[i] = (gi < NN * KK) ? dis[gi] : 0.f;
    }
    __syncthreads();

    // scaler[n] = tanh(att_w . dis[n] + att_b) + 1 = 2*sigmoid(2z)
    if (t < 128) {
        float z = att_b[0];
        #pragma unroll
        for (int k = 0; k < KK; k++) z += att_w[k] * disL[t * KK + k];
        scalerL[t] = 2.f / (1.f + __expf(-2.f * z));
    }
    __syncthreads();

    // sup[n][k] = 2*sigmoid(-dis*scaler)
    for (int i = t; i < 128 * KK; i += 256) {
        const int gi = n0 * KK + i;
        if (gi < NN * KK)
            g_sup[gi] = 2.f / (1.f + __expf(disL[i] * scalerL[i / KK]));
    }

    // ---- GEMM: 2 adjacent channels x 16 nodes per thread ----
    const int c2 = t & 31;     // channel pair: channels 2*c2, 2*c2+1
    const int g  = t >> 5;     // node group 0..7 -> nodes g*16 .. g*16+15

    float aA0[16], aA1[16], aB0[16], aB1[16];
    #pragma unroll
    for (int j = 0; j < 16; j++) { aA0[j]=0.f; aA1[j]=0.f; aB0[j]=0.f; aB1[j]=0.f; }

    for (int ci = 0; ci < 64; ci++) {
        const float2 a  = *(const float2*)&At[ci][c2 * 2];
        const float2 w2 = *(const float2*)&Bt[ci][c2 * 2];
        const float4* xr = (const float4*)&xt[ci][g * 16];
        #pragma unroll
        for (int q = 0; q < 4; q++) {
            float4 xv = xr[q];
            aA0[q*4+0] += a.x*xv.x;  aA1[q*4+0] += a.y*xv.x;
            aB0[q*4+0] += w2.x*xv.x; aB1[q*4+0] += w2.y*xv.x;
            aA0[q*4+1] += a.x*xv.y;  aA1[q*4+1] += a.y*xv.y;
            aB0[q*4+1] += w2.x*xv.y; aB1[q*4+1] += w2.y*xv.y;
            aA0[q*4+2] += a.x*xv.z;  aA1[q*4+2] += a.y*xv.z;
            aB0[q*4+2] += w2.x*xv.z; aB1[q*4+2] += w2.y*xv.z;
            aA0[q*4+3] += a.x*xv.w;  aA1[q*4+3] += a.y*xv.w;
            aB0[q*4+3] += w2.x*xv.w; aB1[q*4+3] += w2.y*xv.w;
        }
    }

    const float b0 = b[c2 * 2], b1 = b[c2 * 2 + 1];
    unsigned int* yA32 = (unsigned int*)g_poolA;   // [NN][32] channel-pairs
    unsigned int* yB32 = (unsigned int*)g_poolB;
    #pragma unroll
    for (int j = 0; j < 16; j++) {
        const int n = n0 + g * 16 + j;
        if (n < NN) {
            yA32[n * 32 + c2] = (unsigned int)f2bf(aA0[j] + b0)
                              | ((unsigned int)f2bf(aA1[j] + b1) << 16);
            yB32[n * 32 + c2] = (unsigned int)f2bf(aB0[j])
                              | ((unsigned int)f2bf(aB1[j]) << 16);
        }
    }
}

// ---------------------------------------------------------------------------
// Kernel 2 (round-0 proven geometry): 16 nodes/block, 4 nodes/wave,
// slot-parallel gather (4 edge slots x 16 channel-quads), shfl broadcasts,
// 10 uint2 gathers in flight per node. Full 128 B/endpoint = 1 cache line.
// Deltas vs round 0: sup loaded from g_sup (tanh + 20-wide reduce hoisted to
// prep); nontemporal on index/sup/out streams; byte offsets pre-scaled.
// ---------------------------------------------------------------------------
__global__ __launch_bounds__(256) void edge_kernel(
    const int* __restrict__ ej,      // edge_index[0] : [NN][KK]  (x_j -> B pool)
    const int* __restrict__ ei,      // edge_index[1] : [NN][KK]  (x_i -> A pool)
    float* __restrict__ out)         // [64][NN]
{
    __shared__ float tile[16][68];

    const int t    = threadIdx.x;
    const int lane = t & 63;
    const int w    = t >> 6;            // wave 0..3
    const int g    = lane >> 4;         // edge slot 0..3
    const int l    = lane & 15;         // channel quad 0..15
    const int n0   = blockIdx.x * 16;   // grid 3125, no tail
    const int nb   = n0 + w * 4;

    const char* pA = (const char*)g_poolA;
    const char* pB = (const char*)g_poolB;

    int offI[4], offJ[4]; float sup4[4];
    #pragma unroll
    for (int s = 0; s < 4; s++) {
        const int n = nb + s;
        int ii = 0, jj = 0; float sp = 0.f;
        if (lane < KK) {
            ii = __builtin_nontemporal_load(&ei[n * KK + lane]);
            jj = __builtin_nontemporal_load(&ej[n * KK + lane]);
            sp = __builtin_nontemporal_load(&g_sup[n * KK + lane]);
        }
        offI[s] = ii << 7;      // byte offset: node * 128
        offJ[s] = jj << 7;
        sup4[s] = sp;
    }

    #pragma unroll
    for (int s = 0; s < 4; s++) {
        float4 m = {0.f, 0.f, 0.f, 0.f};
        #pragma unroll
        for (int kb = 0; kb < 5; kb++) {
            const int   src = kb * 4 + g;       // 0..19
            const int   oi  = __shfl(offI[s], src);
            const int   oj  = __shfl(offJ[s], src);
            const float sp  = __shfl(sup4[s], src);
            const uint2 a   = *(const uint2*)(pA + oi + l * 8);
            const uint2 bb  = *(const uint2*)(pB + oj + l * 8);
            float v;
            v = fmaxf(bfl(a.x) + bfl(bb.x), 0.f) * sp;  m.x = fmaxf(m.x, v);
            v = fmaxf(bfh(a.x) + bfh(bb.x), 0.f) * sp;  m.y = fmaxf(m.y, v);
            v = fmaxf(bfl(a.y) + bfl(bb.y), 0.f) * sp;  m.z = fmaxf(m.z, v);
            v = fmaxf(bfh(a.y) + bfh(bb.y), 0.f) * sp;  m.w = fmaxf(m.w, v);
        }
        #pragma unroll
        for (int mask = 16; mask <= 32; mask <<= 1) {
            m.x = fmaxf(m.x, __shfl_xor(m.x, mask));
            m.y = fmaxf(m.y, __shfl_xor(m.y, mask));
            m.z = fmaxf(m.z, __shfl_xor(m.z, mask));
            m.w = fmaxf(m.w, __shfl_xor(m.w, mask));
        }
        if (g == 0) *(float4*)&tile[w * 4 + s][l * 4] = m;
    }
    __syncthreads();

    #pragma unroll
    for (int it = 0; it < 4; it++) {
        const int c  = it * 16 + (t >> 4);
        const int nl = t & 15;
        __builtin_nontemporal_store(tile[nl][c],
                                    &out[(size_t)c * NN + n0 + nl]);
    }
}

extern "C" void kernel_launch(void* const* d_in, const int* in_sizes, int n_in,
                              void* d_out, int out_size, void* d_ws, size_t ws_size,
                              hipStream_t stream) {
    const float* x     = (const float*)d_in[0];
    const int*   e     = (const int*)d_in[1];    // [2][NN][KK]
    const float* dis   = (const float*)d_in[2];
    const float* W     = (const float*)d_in[3];
    const float* b     = (const float*)d_in[4];
    const float* att_w = (const float*)d_in[5];
    const float* att_b = (const float*)d_in[6];
    float* out = (float*)d_out;

    (void)d_ws; (void)ws_size;   // intentionally unused: static __device__ scratch

    prep_kernel<<<(NN + 127) / 128, 256, 0, stream>>>(x, W, b, dis, att_w, att_b);
    edge_kernel<<<NN / 16, 256, 0, stream>>>(e, e + NN * KK, out);
}

// Round 3
// 133.371 us; speedup vs baseline: 1.0842x; 1.0008x over previous
//
#include <hip/hip_runtime.h>

#define NN 50000
#define KK 20

// Static device scratch (d_ws poison fill happens regardless; static keeps
// layout control and frees us from ws entirely).
__device__ __align__(256) ushort g_poolA[NN * 64];   // [NN][64] bf16, node-major
__device__ __align__(256) ushort g_poolB[NN * 64];
__device__ __align__(256) float  g_sup[NN * KK];     // precomputed suppression

static __device__ __forceinline__ ushort f2bf(float f) {
    unsigned int u = __float_as_uint(f);
    unsigned int r = (u + 0x7FFFu + ((u >> 16) & 1u)) >> 16;   // RNE
    return (ushort)r;
}
static __device__ __forceinline__ float bfl(unsigned int u) {   // low bf16 -> f32
    return __uint_as_float(u << 16);
}
static __device__ __forceinline__ float bfh(unsigned int u) {   // high bf16 -> f32
    return __uint_as_float(u & 0xffff0000u);
}

// ---------------------------------------------------------------------------
// Kernel 1: UNCHANGED from round 2 (yA/yB GEMM + sup precompute).
// ---------------------------------------------------------------------------
__global__ __launch_bounds__(256) void prep_kernel(
    const float* __restrict__ x,    // [64][NN]
    const float* __restrict__ W,    // [64][128]
    const float* __restrict__ b,    // [64]
    const float* __restrict__ dis,  // [NN][KK]
    const float* __restrict__ att_w,// [KK]
    const float* __restrict__ att_b)// [1]
{
    __shared__ float At[64][66];    // W1-W2, transposed
    __shared__ float Bt[64][66];    // W2, transposed
    __shared__ float xt[64][132];   // x tile, 128 nodes
    __shared__ float disL[128 * KK];
    __shared__ float scalerL[128];

    const int t  = threadIdx.x;
    const int n0 = blockIdx.x * 128;     // grid 391; tail block has 80 valid

    for (int i = t; i < 64 * 64; i += 256) {
        int c = i >> 6, ci = i & 63;
        float w1 = W[c * 128 + ci];
        float w2 = W[c * 128 + 64 + ci];
        At[ci][c] = w1 - w2;
        Bt[ci][c] = w2;
    }
    {
        const int q  = t & 31;           // float4 index within the 128 nodes
        const int cb = t >> 5;           // 0..7
        const float4* x4 = (const float4*)x;   // [64][12500] float4
        const int nq = (n0 >> 2) + q;
        #pragma unroll
        for (int i = 0; i < 8; i++) {
            const int ci = cb * 8 + i;
            float4 v = (nq < 12500) ? x4[ci * 12500 + nq]
                                    : float4{0.f, 0.f, 0.f, 0.f};
            *(float4*)&xt[ci][q * 4] = v;
        }
    }
    for (int i = t; i < 128 * KK; i += 256) {
        const int gi = n0 * KK + i;
        disL[i] = (gi < NN * KK) ? dis[gi] : 0.f;
    }
    __syncthreads();

    // scaler[n] = tanh(att_w . dis[n] + att_b) + 1 = 2*sigmoid(2z)
    if (t < 128) {
        float z = att_b[0];
        #pragma unroll
        for (int k = 0; k < KK; k++) z += att_w[k] * disL[t * KK + k];
        scalerL[t] = 2.f / (1.f + __expf(-2.f * z));
    }
    __syncthreads();

    // sup[n][k] = 2*sigmoid(-dis*scaler)
    for (int i = t; i < 128 * KK; i += 256) {
        const int gi = n0 * KK + i;
        if (gi < NN * KK)
            g_sup[gi] = 2.f / (1.f + __expf(disL[i] * scalerL[i / KK]));
    }

    // ---- GEMM: 2 adjacent channels x 16 nodes per thread ----
    const int c2 = t & 31;     // channel pair: channels 2*c2, 2*c2+1
    const int g  = t >> 5;     // node group 0..7 -> nodes g*16 .. g*16+15

    float aA0[16], aA1[16], aB0[16], aB1[16];
    #pragma unroll
    for (int j = 0; j < 16; j++) { aA0[j]=0.f; aA1[j]=0.f; aB0[j]=0.f; aB1[j]=0.f; }

    for (int ci = 0; ci < 64; ci++) {
        const float2 a  = *(const float2*)&At[ci][c2 * 2];
        const float2 w2 = *(const float2*)&Bt[ci][c2 * 2];
        const float4* xr = (const float4*)&xt[ci][g * 16];
        #pragma unroll
        for (int q = 0; q < 4; q++) {
            float4 xv = xr[q];
            aA0[q*4+0] += a.x*xv.x;  aA1[q*4+0] += a.y*xv.x;
            aB0[q*4+0] += w2.x*xv.x; aB1[q*4+0] += w2.y*xv.x;
            aA0[q*4+1] += a.x*xv.y;  aA1[q*4+1] += a.y*xv.y;
            aB0[q*4+1] += w2.x*xv.y; aB1[q*4+1] += w2.y*xv.y;
            aA0[q*4+2] += a.x*xv.z;  aA1[q*4+2] += a.y*xv.z;
            aB0[q*4+2] += w2.x*xv.z; aB1[q*4+2] += w2.y*xv.z;
            aA0[q*4+3] += a.x*xv.w;  aA1[q*4+3] += a.y*xv.w;
            aB0[q*4+3] += w2.x*xv.w; aB1[q*4+3] += w2.y*xv.w;
        }
    }

    const float b0 = b[c2 * 2], b1 = b[c2 * 2 + 1];
    unsigned int* yA32 = (unsigned int*)g_poolA;   // [NN][32] channel-pairs
    unsigned int* yB32 = (unsigned int*)g_poolB;
    #pragma unroll
    for (int j = 0; j < 16; j++) {
        const int n = n0 + g * 16 + j;
        if (n < NN) {
            yA32[n * 32 + c2] = (unsigned int)f2bf(aA0[j] + b0)
                              | ((unsigned int)f2bf(aA1[j] + b1) << 16);
            yB32[n * 32 + c2] = (unsigned int)f2bf(aB0[j])
                              | ((unsigned int)f2bf(aB1[j]) << 16);
        }
    }
}

// ---------------------------------------------------------------------------
// Kernel 2: same geometry as round 2 (16 nodes/block, 4 edge slots x 16
// channel-quads, full 128 B/endpoint). DELTA: deep-MLP restructure — per
// node-slot, precompute all 10 shfl'd offsets, issue all 10 gathers into
// explicit register arrays (forces ~20 live data VGPRs -> true overlap of
// the random-gather latency), overlap sup shfls with load latency, then
// compute. Identical math and addresses; VGPR ~24 -> ~56 (still full occ).
// ---------------------------------------------------------------------------
__global__ __launch_bounds__(256) void edge_kernel(
    const int* __restrict__ ej,      // edge_index[0] : [NN][KK]  (x_j -> B pool)
    const int* __restrict__ ei,      // edge_index[1] : [NN][KK]  (x_i -> A pool)
    float* __restrict__ out)         // [64][NN]
{
    __shared__ float tile[16][68];

    const int t    = threadIdx.x;
    const int lane = t & 63;
    const int w    = t >> 6;            // wave 0..3
    const int g    = lane >> 4;         // edge slot 0..3
    const int l    = lane & 15;         // channel quad 0..15
    const int n0   = blockIdx.x * 16;   // grid 3125, no tail
    const int nb   = n0 + w * 4;

    const char* pA = (const char*)g_poolA;
    const char* pB = (const char*)g_poolB;

    int offI[4], offJ[4]; float sup4[4];
    #pragma unroll
    for (int s = 0; s < 4; s++) {
        const int n = nb + s;
        int ii = 0, jj = 0; float sp = 0.f;
        if (lane < KK) {
            ii = __builtin_nontemporal_load(&ei[n * KK + lane]);
            jj = __builtin_nontemporal_load(&ej[n * KK + lane]);
            sp = __builtin_nontemporal_load(&g_sup[n * KK + lane]);
        }
        offI[s] = ii << 7;      // byte offset: node * 128
        offJ[s] = jj << 7;
        sup4[s] = sp;
    }

    #pragma unroll
    for (int s = 0; s < 4; s++) {
        // 1) all 10 gather addresses up front
        int oi[5], oj[5];
        #pragma unroll
        for (int kb = 0; kb < 5; kb++) {
            const int src = kb * 4 + g;       // 0..19
            oi[kb] = __shfl(offI[s], src);
            oj[kb] = __shfl(offJ[s], src);
        }
        // 2) all 10 gathers issued back-to-back, results live in arrays
        uint2 ga[5], gb[5];
        #pragma unroll
        for (int kb = 0; kb < 5; kb++) {
            ga[kb] = *(const uint2*)(pA + oi[kb] + l * 8);
            gb[kb] = *(const uint2*)(pB + oj[kb] + l * 8);
        }
        // 3) sup broadcasts overlap the gather latency
        float sp[5];
        #pragma unroll
        for (int kb = 0; kb < 5; kb++) sp[kb] = __shfl(sup4[s], kb * 4 + g);
        // 4) math
        float4 m = {0.f, 0.f, 0.f, 0.f};
        #pragma unroll
        for (int kb = 0; kb < 5; kb++) {
            const uint2 a  = ga[kb];
            const uint2 bb = gb[kb];
            float v;
            v = fmaxf(bfl(a.x) + bfl(bb.x), 0.f) * sp[kb];  m.x = fmaxf(m.x, v);
            v = fmaxf(bfh(a.x) + bfh(bb.x), 0.f) * sp[kb];  m.y = fmaxf(m.y, v);
            v = fmaxf(bfl(a.y) + bfl(bb.y), 0.f) * sp[kb];  m.z = fmaxf(m.z, v);
            v = fmaxf(bfh(a.y) + bfh(bb.y), 0.f) * sp[kb];  m.w = fmaxf(m.w, v);
        }
        #pragma unroll
        for (int mask = 16; mask <= 32; mask <<= 1) {
            m.x = fmaxf(m.x, __shfl_xor(m.x, mask));
            m.y = fmaxf(m.y, __shfl_xor(m.y, mask));
            m.z = fmaxf(m.z, __shfl_xor(m.z, mask));
            m.w = fmaxf(m.w, __shfl_xor(m.w, mask));
        }
        if (g == 0) *(float4*)&tile[w * 4 + s][l * 4] = m;
    }
    __syncthreads();

    #pragma unroll
    for (int it = 0; it < 4; it++) {
        const int c  = it * 16 + (t >> 4);
        const int nl = t & 15;
        __builtin_nontemporal_store(tile[nl][c],
                                    &out[(size_t)c * NN + n0 + nl]);
    }
}

extern "C" void kernel_launch(void* const* d_in, const int* in_sizes, int n_in,
                              void* d_out, int out_size, void* d_ws, size_t ws_size,
                              hipStream_t stream) {
    const float* x     = (const float*)d_in[0];
    const int*   e     = (const int*)d_in[1];    // [2][NN][KK]
    const float* dis   = (const float*)d_in[2];
    const float* W     = (const float*)d_in[3];
    const float* b     = (const float*)d_in[4];
    const float* att_w = (const float*)d_in[5];
    const float* att_b = (const float*)d_in[6];
    float* out = (float*)d_out;

    (void)d_ws; (void)ws_size;   // intentionally unused: static __device__ scratch

    prep_kernel<<<(NN + 127) / 128, 256, 0, stream>>>(x, W, b, dis, att_w, att_b);
    edge_kernel<<<NN / 16, 256, 0, stream>>>(e, e + NN * KK, out);
}